// Round 6
// baseline (1139.763 us; speedup 1.0000x reference)
//
#include <hip/hip_runtime.h>

typedef __attribute__((ext_vector_type(8))) short short8;
typedef __attribute__((ext_vector_type(4))) float f32x4;
typedef __attribute__((ext_vector_type(16))) float f32x16;

// ---------- helpers ----------
__device__ __forceinline__ unsigned short f2bf(float f) {
    union { float f; unsigned int u; } v; v.f = f;
    unsigned int u = v.u;
    unsigned int r = (u + 0x7FFFu + ((u >> 16) & 1u)) >> 16;
    return (unsigned short)r;
}
__device__ __forceinline__ float bf2f(unsigned short u) {
    union { unsigned int u; float f; } v; v.u = ((unsigned int)u) << 16;
    return v.f;
}
__device__ __forceinline__ void load_lds16(const void* g, void* l) {
    __builtin_amdgcn_global_load_lds(
        (const __attribute__((address_space(1))) void*)g,
        (__attribute__((address_space(3))) void*)l, 16, 0, 0);
}
#define BAR() asm volatile("s_barrier" ::: "memory")

// ---------- fp32 -> bf16 convert ----------
__global__ __launch_bounds__(256) void conv_bf16(const float* __restrict__ in,
                                                 unsigned short* __restrict__ out, int n4) {
    int i = blockIdx.x * 256 + threadIdx.x;
    if (i >= n4) return;
    float4 v = ((const float4*)in)[i];
    ushort4 o;
    o.x = f2bf(v.x); o.y = f2bf(v.y); o.z = f2bf(v.z); o.w = f2bf(v.w);
    ((ushort4*)out)[i] = o;
}

// ---------- 256x256 GEMM, 32x32x16 MFMA, 4-deep BK=32 pipeline ----------
// C[M,N] = A[M,K] * B[N,K]^T, bf16 in, fp32 acc.
// 8 waves (2M x 4N), per-wave out 128x64 = 4x2 tiles of 32x32. acc = 8 x f32x16.
// LDS 128 KiB = 4 bufs x {A 16KB, B 16KB}; k-half-major tile layout:
//   A region: byte = ks*8192 + hi*4096 + row*16   (row 0..255, element
//   k = ks*16 + hi*8 + e). Fragment read for lane (lr,hi):
//   base + hi*4096 + lr*16 -> each 16-lane group reads 256B contiguous
//   (16 distinct 16B slots, all 32 banks, 2 lanes/bank) => conflict-free
//   [R5 lesson: [row][32B] layout gave quarter-waves only 16 banks, 4-way].
// Staging keeps linear dest tid*16; global source row = tid&255,
//   k-half = tid>>8 -> src = g + (tid&255)*K + (tid>>8)*8 (+t*32, +16 for ks1).
// Pipeline (unchanged ledger from R5): iter i covers tiles T..T+3 in bufs
// 0..3; 8 phases, 1 k16-step each; RD in phase p reads k-step p+1.
// Stage schedule (2 loads/phase): P8,P1: T+3 -> buf3; P2,P3: T+4 -> buf0;
//   P4,P5: T+5 -> buf1; P6,P7: T+6 -> buf2.
// end-P1/P3/P5/P7 vmcnt(8)+lgkmcnt(0) retire T+1/T+2/T+3/T+4; every waited
// load is >=4 phases old. Last iter: waits vmcnt(4)@P3, vmcnt(0)@P5.
template <bool OUT_BF16>
__global__ __launch_bounds__(512, 2) void gemm256(const unsigned short* __restrict__ A,
                                                  const unsigned short* __restrict__ B,
                                                  void* __restrict__ Cv,
                                                  int M, int N, int K, int NBN) {
    __shared__ __align__(16) char smem[131072];
    const int tid = threadIdx.x;
    const int lane = tid & 63, wv = tid >> 6;
    const int wm = wv >> 2, wn = wv & 3;
    const int lr = lane & 31, hi = lane >> 5;

    // bijective XCD swizzle (m204)
    const int nwg = gridDim.x, bid = blockIdx.x;
    const int q = nwg >> 3, r = nwg & 7, xcd = bid & 7, lid = bid >> 3;
    const int wg = (xcd < r ? xcd * (q + 1) : r * (q + 1) + (xcd - r) * q) + lid;
    const int bm = wg / NBN, bn = wg % NBN;

    const unsigned short* gA = A + (size_t)bm * 256 * K;
    const unsigned short* gB = B + (size_t)bn * 256 * K;
    // stage source: row = tid&255, k-half = tid>>8
    const unsigned short* sA = gA + (size_t)(tid & 255) * K + (tid >> 8) * 8;
    const unsigned short* sB = gB + (size_t)(tid & 255) * K + (tid >> 8) * 8;

    f32x16 acc[4][2] = {};
    short8 a[2][4], b[2][2];

    // fragment read bases (bytes) within a ks-block
    const int raoff = hi * 4096 + wm * 2048 + lr * 16;            // + mt*512
    const int rboff = 16384 + hi * 4096 + wn * 1024 + lr * 16;    // + nt*512

#define STAGE_A(buf, t) do { \
    load_lds16(sA + (t) * 32,      smem + (buf) * 32768 + tid * 16); \
    load_lds16(sA + (t) * 32 + 16, smem + (buf) * 32768 + 8192 + tid * 16); } while (0)
#define STAGE_B(buf, t) do { \
    load_lds16(sB + (t) * 32,      smem + (buf) * 32768 + 16384 + tid * 16); \
    load_lds16(sB + (t) * 32 + 16, smem + (buf) * 32768 + 24576 + tid * 16); } while (0)
#define RD(f, buf, ks) do { \
    const char* _pa = smem + (buf) * 32768 + (ks) * 8192 + raoff; \
    a[f][0] = *(const short8*)(_pa); \
    a[f][1] = *(const short8*)(_pa + 512); \
    a[f][2] = *(const short8*)(_pa + 1024); \
    a[f][3] = *(const short8*)(_pa + 1536); \
    const char* _pb = smem + (buf) * 32768 + (ks) * 8192 + rboff; \
    b[f][0] = *(const short8*)(_pb); \
    b[f][1] = *(const short8*)(_pb + 512); } while (0)
#define MMF(f) do { \
    __builtin_amdgcn_s_setprio(1); \
    acc[0][0] = __builtin_amdgcn_mfma_f32_32x32x16_bf16(a[f][0], b[f][0], acc[0][0], 0, 0, 0); \
    acc[0][1] = __builtin_amdgcn_mfma_f32_32x32x16_bf16(a[f][0], b[f][1], acc[0][1], 0, 0, 0); \
    acc[1][0] = __builtin_amdgcn_mfma_f32_32x32x16_bf16(a[f][1], b[f][0], acc[1][0], 0, 0, 0); \
    acc[1][1] = __builtin_amdgcn_mfma_f32_32x32x16_bf16(a[f][1], b[f][1], acc[1][1], 0, 0, 0); \
    acc[2][0] = __builtin_amdgcn_mfma_f32_32x32x16_bf16(a[f][2], b[f][0], acc[2][0], 0, 0, 0); \
    acc[2][1] = __builtin_amdgcn_mfma_f32_32x32x16_bf16(a[f][2], b[f][1], acc[2][1], 0, 0, 0); \
    acc[3][0] = __builtin_amdgcn_mfma_f32_32x32x16_bf16(a[f][3], b[f][0], acc[3][0], 0, 0, 0); \
    acc[3][1] = __builtin_amdgcn_mfma_f32_32x32x16_bf16(a[f][3], b[f][1], acc[3][1], 0, 0, 0); \
    __builtin_amdgcn_s_setprio(0); } while (0)
#define WAIT_V8LG() asm volatile("s_waitcnt vmcnt(8) lgkmcnt(0)" ::: "memory")

    // prologue: t0 (A,B), t1, t2 fully; t3 A-half. 14 loads.
    STAGE_A(0, 0); STAGE_B(0, 0);
    STAGE_A(1, 1); STAGE_B(1, 1);
    STAGE_A(2, 2); STAGE_B(2, 2);
    STAGE_A(3, 3);
    asm volatile("s_waitcnt vmcnt(10)" ::: "memory");   // retire t0
    BAR();
    RD(0, 0, 0);

    const int NIT = K >> 7;  // K/128
    for (int i = 0; i < NIT; ++i) {
        const bool last = (i == NIT - 1);
        const int T = 4 * i;
        // P1
        RD(1, 0, 1);
        STAGE_B(3, T + 3);
        MMF(0);
        WAIT_V8LG();
        BAR();
        // P2
        RD(0, 1, 0);
        if (!last) STAGE_A(0, T + 4);
        MMF(1);
        BAR();
        // P3
        RD(1, 1, 1);
        if (!last) STAGE_B(0, T + 4);
        MMF(0);
        if (!last) WAIT_V8LG();
        else       asm volatile("s_waitcnt vmcnt(4) lgkmcnt(0)" ::: "memory");
        BAR();
        // P4
        RD(0, 2, 0);
        if (!last) STAGE_A(1, T + 5);
        MMF(1);
        BAR();
        // P5
        RD(1, 2, 1);
        if (!last) STAGE_B(1, T + 5);
        MMF(0);
        if (!last) WAIT_V8LG();
        else       asm volatile("s_waitcnt vmcnt(0) lgkmcnt(0)" ::: "memory");
        BAR();
        // P6
        RD(0, 3, 0);
        if (!last) STAGE_A(2, T + 6);
        MMF(1);
        BAR();
        // P7
        RD(1, 3, 1);
        if (!last) STAGE_B(2, T + 6);
        MMF(0);
        if (!last) WAIT_V8LG();
        BAR();
        // P8
        if (!last) {
            RD(0, 0, 0);
            STAGE_A(3, T + 7);
        }
        MMF(1);
        BAR();
    }
#undef STAGE_A
#undef STAGE_B
#undef RD
#undef MMF
#undef WAIT_V8LG

    // epilogue: C/D layout (32x32): col = lane&31, row = (r&3) + 8*(r>>2) + 4*hi
    const size_t row0 = (size_t)bm * 256 + wm * 128 + hi * 4;
    const int col0 = bn * 256 + wn * 64 + lr;
#pragma unroll
    for (int mt = 0; mt < 4; ++mt)
#pragma unroll
        for (int nt = 0; nt < 2; ++nt)
#pragma unroll
            for (int r2 = 0; r2 < 16; ++r2) {
                size_t row = row0 + mt * 32 + (r2 & 3) + ((r2 >> 2) << 3);
                size_t idx = row * (size_t)N + col0 + nt * 32;
                float v = acc[mt][nt][r2];
                if (OUT_BF16) ((unsigned short*)Cv)[idx] = f2bf(v);
                else          ((float*)Cv)[idx] = v;
            }
}

// ---------- RoPE (interleaved, first 64 dims) + repack q,k -> [b,h,s,d] ----------
__global__ __launch_bounds__(256) void rope_repack(const unsigned short* __restrict__ qkv,
                                                   const int* __restrict__ positions,
                                                   unsigned short* __restrict__ qp,
                                                   unsigned short* __restrict__ kp) {
    int r = blockIdx.x * 4 + (threadIdx.x >> 6);   // (b,s,h) row, 0..65535
    int h = r & 15, s = (r >> 4) & 2047, b = r >> 15;
    int d = (threadIdx.x & 63) * 4;
    const unsigned short* src = qkv + (size_t)(b * 2048 + s) * 12288 + h * 256 + d;
    ushort4 q = *(const ushort4*)src;
    ushort4 k = *(const ushort4*)(src + 4096);
    if (d < 64) {
        float pos = (float)positions[s];
        const float LF = 0.4152410118609203f;      // log2(10000)/32
        float i0 = (float)(d >> 1);
        float a0 = pos * exp2f(-i0 * LF);
        float a1 = pos * exp2f(-(i0 + 1.0f) * LF);
        float c0 = cosf(a0), s0 = sinf(a0), c1 = cosf(a1), s1 = sinf(a1);
        float qx = bf2f(q.x), qy = bf2f(q.y), qz = bf2f(q.z), qw = bf2f(q.w);
        q.x = f2bf(qx * c0 - qy * s0); q.y = f2bf(qx * s0 + qy * c0);
        q.z = f2bf(qz * c1 - qw * s1); q.w = f2bf(qz * s1 + qw * c1);
        float kx = bf2f(k.x), ky = bf2f(k.y), kz = bf2f(k.z), kw = bf2f(k.w);
        k.x = f2bf(kx * c0 - ky * s0); k.y = f2bf(kx * s0 + ky * c0);
        k.z = f2bf(kz * c1 - kw * s1); k.w = f2bf(kz * s1 + kw * c1);
    }
    size_t dst = ((size_t)((b * 16 + h) * 2048 + s)) * 256 + d;
    *(ushort4*)&qp[dst] = q;
    *(ushort4*)&kp[dst] = k;
}

// ---------- V transpose -> [b,h,d,s] ----------
__global__ __launch_bounds__(256) void v_transpose(const unsigned short* __restrict__ qkv,
                                                   unsigned short* __restrict__ vt) {
    int bid = blockIdx.x;
    int dt = bid & 3, st = (bid >> 2) & 31, bh = bid >> 7;
    int b = bh >> 4, h = bh & 15;
    __shared__ unsigned short t[64][72];
    int tid = threadIdx.x;
#pragma unroll
    for (int rep = 0; rep < 16; ++rep) {
        int idx = rep * 256 + tid;
        int r = idx >> 6, c = idx & 63;   // r: s-offset, c: d-offset
        t[r][c] = qkv[(size_t)(b * 2048 + st * 64 + r) * 12288 + 8192 + h * 256 + dt * 64 + c];
    }
    __syncthreads();
#pragma unroll
    for (int rep = 0; rep < 16; ++rep) {
        int idx = rep * 256 + tid;
        int r = idx >> 6, c = idx & 63;   // r: d-offset, c: s-offset
        vt[(size_t)(bh * 256 + dt * 64 + r) * 2048 + st * 64 + c] = t[c][r];
    }
}

// ---------- flash attention (causal), 4 waves x 16 q-rows, KV tile 32 ----------
__global__ __launch_bounds__(256) void attn_fwd(const unsigned short* __restrict__ Qp,
                                                const unsigned short* __restrict__ Kp,
                                                const unsigned short* __restrict__ Vt,
                                                unsigned short* __restrict__ Oa) {
    __shared__ __align__(16) unsigned short Ks[32 * 256];
    __shared__ __align__(16) unsigned short Vs[256 * 32];
    __shared__ __align__(16) unsigned short Ps[4][16 * 32];
    const int tid = threadIdx.x, lane = tid & 63, wv = tid >> 6;
    const int bh = blockIdx.x, qt = blockIdx.y;
    const int fr = lane & 15, fo = (lane >> 4) * 8;
    const unsigned short* Qb = Qp + (size_t)bh * 2048 * 256;
    const unsigned short* Kb = Kp + (size_t)bh * 2048 * 256;
    const unsigned short* Vb = Vt + (size_t)bh * 256 * 2048;
    const int qbase = qt * 64 + wv * 16;

    short8 qf[8];
#pragma unroll
    for (int c = 0; c < 8; ++c)
        qf[c] = *(const short8*)&Qb[(size_t)(qbase + fr) * 256 + c * 32 + fo];

    f32x4 o_acc[16] = {};
    float m_run[4] = {-1e30f, -1e30f, -1e30f, -1e30f};
    float l_run[4] = {0.f, 0.f, 0.f, 0.f};

    const int nkv = qt * 64 + 64;
    for (int kv0 = 0; kv0 < nkv; kv0 += 32) {
#pragma unroll
        for (int i = 0; i < 4; ++i) {
            int eb = (wv * 4 + i) * 512;
            load_lds16(&Kb[(size_t)(kv0 + (eb >> 8) + (lane >> 5)) * 256 + (lane & 31) * 8], &Ks[eb]);
        }
#pragma unroll
        for (int i = 0; i < 4; ++i) {
            int eb = (wv * 4 + i) * 512;
            load_lds16(&Vb[(size_t)((eb >> 5) + (lane >> 2)) * 2048 + kv0 + (lane & 3) * 8], &Vs[eb]);
        }
        __syncthreads();

        f32x4 sc[2] = {};
#pragma unroll
        for (int t = 0; t < 2; ++t)
#pragma unroll
            for (int c = 0; c < 8; ++c) {
                short8 kf = *(const short8*)&Ks[(t * 16 + fr) * 256 + c * 32 + fo];
                sc[t] = __builtin_amdgcn_mfma_f32_16x16x32_bf16(qf[c], kf, sc[t], 0, 0, 0);
            }

        float sv[2][4];
#pragma unroll
        for (int j = 0; j < 4; ++j) {
            int qi = qbase + ((lane >> 4) << 2) + j;
#pragma unroll
            for (int t = 0; t < 2; ++t) {
                float x = sc[t][j] * 0.0625f;
                int kvi = kv0 + t * 16 + fr;
                sv[t][j] = (kvi > qi) ? -1e30f : x;
            }
            float pm = fmaxf(sv[0][j], sv[1][j]);
#pragma unroll
            for (int off = 1; off < 16; off <<= 1)
                pm = fmaxf(pm, __shfl_xor(pm, off));
            float mn = fmaxf(m_run[j], pm);
            float al = __expf(m_run[j] - mn);
            m_run[j] = mn;
            float rs = 0.f;
#pragma unroll
            for (int t = 0; t < 2; ++t) {
                float p = __expf(sv[t][j] - mn);
                rs += p;
                Ps[wv][(((lane >> 4) << 2) + j) * 32 + t * 16 + fr] = f2bf(p);
            }
#pragma unroll
            for (int off = 1; off < 16; off <<= 1)
                rs += __shfl_xor(rs, off);
            l_run[j] = l_run[j] * al + rs;
#pragma unroll
            for (int n = 0; n < 16; ++n) o_acc[n][j] *= al;
        }

        short8 pf = *(const short8*)&Ps[wv][fr * 32 + fo];
#pragma unroll
        for (int n = 0; n < 16; ++n) {
            short8 vf = *(const short8*)&Vs[(n * 16 + fr) * 32 + fo];
            o_acc[n] = __builtin_amdgcn_mfma_f32_16x16x32_bf16(pf, vf, o_acc[n], 0, 0, 0);
        }
        __syncthreads();
    }

    const int b = bh >> 4, h = bh & 15;
#pragma unroll
    for (int j = 0; j < 4; ++j) {
        float inv = 1.0f / l_run[j];
        int qrow = qbase + ((lane >> 4) << 2) + j;
        size_t base = ((size_t)(b * 2048 + qrow)) * 4096 + h * 256;
#pragma unroll
        for (int n = 0; n < 16; ++n)
            Oa[base + n * 16 + fr] = f2bf(o_acc[n][j] * inv);
    }
}

// ---------- launch ----------
extern "C" void kernel_launch(void* const* d_in, const int* in_sizes, int n_in,
                              void* d_out, int out_size, void* d_ws, size_t ws_size,
                              hipStream_t stream) {
    const float* hidden = (const float*)d_in[0];
    const int* positions = (const int*)d_in[1];
    const float* w_qkv = (const float*)d_in[2];
    const float* w_out = (const float*)d_in[3];
    float* out = (float*)d_out;

    const size_t MB32 = 33554432;   // 32 MiB
    char* ws = (char*)d_ws;
    unsigned short* hidden_bf = (unsigned short*)ws;              // 32 MB; later attn out
    unsigned short* wqkv_bf   = (unsigned short*)(ws + MB32);     // 96 MB; later q/k/vt
    unsigned short* qkv_bf    = (unsigned short*)(ws + 4 * MB32); // 96 MB; later wout_bf
    unsigned short* qp  = wqkv_bf;                                // 32 MB
    unsigned short* kp  = wqkv_bf + 16777216;                     // 32 MB
    unsigned short* vtp = wqkv_bf + 33554432;                     // 32 MB
    unsigned short* attn_bf = hidden_bf;                          // 32 MB (reuse)
    unsigned short* wout_bf = qkv_bf;                             // 32 MB (reuse)

    // 1. convert hidden (16.7M) and w_qkv (50.3M) to bf16
    conv_bf16<<<16384, 256, 0, stream>>>(hidden, hidden_bf, 4194304);
    conv_bf16<<<49152, 256, 0, stream>>>(w_qkv, wqkv_bf, 12582912);

    // 2. qkv = hidden @ w_qkv^T   (M=4096, N=12288, K=4096), bf16 out
    gemm256<true><<<16 * 48, 512, 0, stream>>>(hidden_bf, wqkv_bf, qkv_bf, 4096, 12288, 4096, 48);

    // 3. RoPE + repack q,k ; transpose v
    rope_repack<<<16384, 256, 0, stream>>>(qkv_bf, positions, qp, kp);
    v_transpose<<<4096, 256, 0, stream>>>(qkv_bf, vtp);

    // 4. causal flash attention -> attn_bf [4096, 4096]
    attn_fwd<<<dim3(32, 32), 256, 0, stream>>>(qp, kp, vtp, attn_bf);

    // 5. convert w_out, final projection (fp32 out)
    conv_bf16<<<16384, 256, 0, stream>>>(w_out, wout_bf, 4194304);
    gemm256<false><<<16 * 16, 512, 0, stream>>>(attn_bf, wout_bf, out, 4096, 4096, 4096, 16);
}

// Round 7
// 884.384 us; speedup vs baseline: 1.2888x; 1.2888x over previous
//
#include <hip/hip_runtime.h>

typedef __attribute__((ext_vector_type(8))) short short8;
typedef __attribute__((ext_vector_type(4))) float f32x4;
typedef __attribute__((ext_vector_type(16))) float f32x16;

// ---------- helpers ----------
__device__ __forceinline__ unsigned short f2bf(float f) {
    union { float f; unsigned int u; } v; v.f = f;
    unsigned int u = v.u;
    unsigned int r = (u + 0x7FFFu + ((u >> 16) & 1u)) >> 16;
    return (unsigned short)r;
}
__device__ __forceinline__ float bf2f(unsigned short u) {
    union { unsigned int u; float f; } v; v.u = ((unsigned int)u) << 16;
    return v.f;
}
__device__ __forceinline__ void load_lds16(const void* g, void* l) {
    __builtin_amdgcn_global_load_lds(
        (const __attribute__((address_space(1))) void*)g,
        (__attribute__((address_space(3))) void*)l, 16, 0, 0);
}
#define BAR() asm volatile("s_barrier" ::: "memory")
#define WAITV(n) asm volatile("s_waitcnt vmcnt(" #n ")" ::: "memory")

// LDS swizzle (R3, measured 0 conflicts): XOR row&7 (bits 7-9 at 128B row
// stride) into the 16B-slot index (bits 4-6). Involution on 16B chunks.
__device__ __forceinline__ int swz(int o) { return o ^ ((o >> 3) & 0x70); }

// ---------- fp32 -> bf16 convert ----------
__global__ __launch_bounds__(256) void conv_bf16(const float* __restrict__ in,
                                                 unsigned short* __restrict__ out, int n4) {
    int i = blockIdx.x * 256 + threadIdx.x;
    if (i >= n4) return;
    float4 v = ((const float4*)in)[i];
    ushort4 o;
    o.x = f2bf(v.x); o.y = f2bf(v.y); o.z = f2bf(v.z); o.w = f2bf(v.w);
    ((ushort4*)out)[i] = o;
}

// ---------- 256x256 GEMM: R3 layout/pipeline + 32x32x16 MFMA ----------
// C[M,N] = A[M,K] * B[N,K]^T, bf16 in, fp32 acc.
// 8 waves (2M x 4N), per-wave out 128x64 = 4mt x 2nt tiles of 32x32.
// LDS 128 KiB: buf0 {A@0,B@32768}, buf1 {A@65536,B@98304}; tile = 256 rows
// x 128B (BK=64), swizzled (swz). Staged linear-dest + inverse-swz source
// (R3, verified). Fragment read: lane(lr=lane&31, hi=lane>>5) reads
// byte = swz(row*128 + ks16*32 + hi*16); slot = (2ks+hi)^(lr&7) ->
// 8 accesses per slot-class over 8-cycle min = balanced, conflict-free.
// Phase plan (2 barriers/phase, as R3-367us): per BK=64 tile, 4 phases x
// 8 MFMA (mh-pair x nt x ks-pair); b[2][4] holds all 8 B-frags per tile
// (read P1/P2), a double-buffered set s0/s1 per phase.
// Stage schedule + vmcnt ledger copied from R3 (verified):
//   P1: A1h0(t1) P2: A1h1(t1) P3: B0h0(t2) P4: B0h1(t2)
//   P5: A0h0(t2) P6: A0h1(t2) P7: B1h0(t3) P8: B1h1(t3)
//   end-P4 vmcnt(4) -> t1 landed; end-P8 vmcnt(4) -> t2 landed.
//   Last iter: P3..P8 stages dropped, end-P4 vmcnt(0).
template <bool OUT_BF16>
__global__ __launch_bounds__(512, 2) void gemm256(const unsigned short* __restrict__ A,
                                                  const unsigned short* __restrict__ B,
                                                  void* __restrict__ Cv,
                                                  int M, int N, int K, int NBN) {
    __shared__ __align__(16) char smem[131072];
    const int tid = threadIdx.x;
    const int lane = tid & 63, wv = tid >> 6;
    const int wm = wv >> 2, wn = wv & 3;
    const int lr = lane & 31, hi = lane >> 5;

    // bijective XCD swizzle (m204)
    const int nwg = gridDim.x, bid = blockIdx.x;
    const int q = nwg >> 3, r = nwg & 7, xcd = bid & 7, lid = bid >> 3;
    const int wg = (xcd < r ? xcd * (q + 1) : r * (q + 1) + (xcd - r) * q) + lid;
    const int bm = wg / NBN, bn = wg % NBN;

    const unsigned short* gA = A + (size_t)bm * 256 * K;
    const unsigned short* gB = B + (size_t)bn * 256 * K;

    // staging geometry: linear LDS dest o -> global element at swz(o)
    int srow[2][2], scol[2][2];
#pragma unroll
    for (int h = 0; h < 2; ++h)
#pragma unroll
        for (int rr = 0; rr < 2; ++rr) {
            int o = h * 16384 + rr * 8192 + tid * 16;
            int osw = swz(o);
            srow[h][rr] = osw >> 7;
            scol[h][rr] = (osw & 127) >> 1;
        }

    f32x16 acc[4][2] = {};
    short8 a[2][2][2];   // [set][mi][ki]
    short8 b[2][4];      // [ni][ks16]

    auto STAGE = [&](const unsigned short* g, int regionBase, int h, int t) {
#pragma unroll
        for (int rr = 0; rr < 2; ++rr)
            load_lds16(g + (size_t)srow[h][rr] * K + t * 64 + scol[h][rr],
                       smem + regionBase + h * 16384 + rr * 8192 + tid * 16);
    };

#define AB_OFF(row, ks16) swz((((row)) << 7) + (ks16) * 32 + hi * 16)
#define RD_A(s, mh, kp, base) do { \
    a[s][0][0] = *(const short8*)(smem + (base) + AB_OFF(wm * 128 + (mh) * 64 + lr,      (kp) * 2));     \
    a[s][0][1] = *(const short8*)(smem + (base) + AB_OFF(wm * 128 + (mh) * 64 + lr,      (kp) * 2 + 1)); \
    a[s][1][0] = *(const short8*)(smem + (base) + AB_OFF(wm * 128 + (mh) * 64 + 32 + lr, (kp) * 2));     \
    a[s][1][1] = *(const short8*)(smem + (base) + AB_OFF(wm * 128 + (mh) * 64 + 32 + lr, (kp) * 2 + 1)); } while (0)
#define RD_B(kp, base) do { \
    b[0][(kp) * 2]     = *(const short8*)(smem + (base) + 32768 + AB_OFF(wn * 64 + lr,      (kp) * 2));     \
    b[0][(kp) * 2 + 1] = *(const short8*)(smem + (base) + 32768 + AB_OFF(wn * 64 + lr,      (kp) * 2 + 1)); \
    b[1][(kp) * 2]     = *(const short8*)(smem + (base) + 32768 + AB_OFF(wn * 64 + 32 + lr, (kp) * 2));     \
    b[1][(kp) * 2 + 1] = *(const short8*)(smem + (base) + 32768 + AB_OFF(wn * 64 + 32 + lr, (kp) * 2 + 1)); } while (0)
#define MM8(s, mh, kp) do { \
    __builtin_amdgcn_s_setprio(1); \
    acc[(mh)*2][0]   = __builtin_amdgcn_mfma_f32_32x32x16_bf16(a[s][0][0], b[0][(kp)*2],   acc[(mh)*2][0],   0, 0, 0); \
    acc[(mh)*2][1]   = __builtin_amdgcn_mfma_f32_32x32x16_bf16(a[s][0][0], b[1][(kp)*2],   acc[(mh)*2][1],   0, 0, 0); \
    acc[(mh)*2+1][0] = __builtin_amdgcn_mfma_f32_32x32x16_bf16(a[s][1][0], b[0][(kp)*2],   acc[(mh)*2+1][0], 0, 0, 0); \
    acc[(mh)*2+1][1] = __builtin_amdgcn_mfma_f32_32x32x16_bf16(a[s][1][0], b[1][(kp)*2],   acc[(mh)*2+1][1], 0, 0, 0); \
    acc[(mh)*2][0]   = __builtin_amdgcn_mfma_f32_32x32x16_bf16(a[s][0][1], b[0][(kp)*2+1], acc[(mh)*2][0],   0, 0, 0); \
    acc[(mh)*2][1]   = __builtin_amdgcn_mfma_f32_32x32x16_bf16(a[s][0][1], b[1][(kp)*2+1], acc[(mh)*2][1],   0, 0, 0); \
    acc[(mh)*2+1][0] = __builtin_amdgcn_mfma_f32_32x32x16_bf16(a[s][1][1], b[0][(kp)*2+1], acc[(mh)*2+1][0], 0, 0, 0); \
    acc[(mh)*2+1][1] = __builtin_amdgcn_mfma_f32_32x32x16_bf16(a[s][1][1], b[1][(kp)*2+1], acc[(mh)*2+1][1], 0, 0, 0); \
    __builtin_amdgcn_s_setprio(0); } while (0)

    const int A0 = 0, B0 = 32768, A1 = 65536, B1 = 98304;

    // prologue: t0 (A,B) -> buf0; t1 B -> buf1. 12 loads.
    STAGE(gA, A0, 0, 0); STAGE(gA, A0, 1, 0);
    STAGE(gB, B0, 0, 0); STAGE(gB, B0, 1, 0);
    STAGE(gB, B1, 0, 1); STAGE(gB, B1, 1, 1);
    WAITV(4);
    BAR();

    const int NIT = K >> 7;  // K/128
    for (int i = 0; i < NIT; ++i) {
        const bool last = (i == NIT - 1);
        const int t1 = 2 * i + 1, t2 = 2 * i + 2, t3 = 2 * i + 3;
        // P1
        RD_A(0, 0, 0, A0); RD_B(0, A0);
        STAGE(gA, A1, 0, t1);
        BAR(); MM8(0, 0, 0); BAR();
        // P2
        RD_A(1, 0, 1, A0); RD_B(1, A0);
        STAGE(gA, A1, 1, t1);
        BAR(); MM8(1, 0, 1); BAR();
        // P3
        RD_A(0, 1, 1, A0);
        if (!last) STAGE(gB, B0, 0, t2);
        BAR(); MM8(0, 1, 1); BAR();
        // P4
        RD_A(1, 1, 0, A0);
        if (!last) STAGE(gB, B0, 1, t2);
        BAR(); MM8(1, 1, 0);
        if (last) WAITV(0); else WAITV(4);
        BAR();
        // P5
        RD_A(0, 0, 0, A1); RD_B(0, A1);
        if (!last) STAGE(gA, A0, 0, t2);
        BAR(); MM8(0, 0, 0); BAR();
        // P6
        RD_A(1, 0, 1, A1); RD_B(1, A1);
        if (!last) STAGE(gA, A0, 1, t2);
        BAR(); MM8(1, 0, 1); BAR();
        // P7
        RD_A(0, 1, 1, A1);
        if (!last) STAGE(gB, B1, 0, t3);
        BAR(); MM8(0, 1, 1); BAR();
        // P8
        RD_A(1, 1, 0, A1);
        if (!last) STAGE(gB, B1, 1, t3);
        BAR(); MM8(1, 1, 0);
        if (!last) WAITV(4);
        BAR();
    }
#undef AB_OFF
#undef RD_A
#undef RD_B
#undef MM8

    // epilogue: 32x32 C/D layout (verified R5/R6): col = lane&31,
    // row = (r2&3) + 8*(r2>>2) + 4*hi
    const size_t row0 = (size_t)bm * 256 + wm * 128 + hi * 4;
    const int col0 = bn * 256 + wn * 64 + lr;
#pragma unroll
    for (int mt = 0; mt < 4; ++mt)
#pragma unroll
        for (int nt = 0; nt < 2; ++nt)
#pragma unroll
            for (int r2 = 0; r2 < 16; ++r2) {
                size_t row = row0 + mt * 32 + (r2 & 3) + ((r2 >> 2) << 3);
                size_t idx = row * (size_t)N + col0 + nt * 32;
                float v = acc[mt][nt][r2];
                if (OUT_BF16) ((unsigned short*)Cv)[idx] = f2bf(v);
                else          ((float*)Cv)[idx] = v;
            }
}

// ---------- RoPE (interleaved, first 64 dims) + repack q,k -> [b,h,s,d] ----------
__global__ __launch_bounds__(256) void rope_repack(const unsigned short* __restrict__ qkv,
                                                   const int* __restrict__ positions,
                                                   unsigned short* __restrict__ qp,
                                                   unsigned short* __restrict__ kp) {
    int r = blockIdx.x * 4 + (threadIdx.x >> 6);   // (b,s,h) row, 0..65535
    int h = r & 15, s = (r >> 4) & 2047, b = r >> 15;
    int d = (threadIdx.x & 63) * 4;
    const unsigned short* src = qkv + (size_t)(b * 2048 + s) * 12288 + h * 256 + d;
    ushort4 q = *(const ushort4*)src;
    ushort4 k = *(const ushort4*)(src + 4096);
    if (d < 64) {
        float pos = (float)positions[s];
        const float LF = 0.4152410118609203f;      // log2(10000)/32
        float i0 = (float)(d >> 1);
        float a0 = pos * exp2f(-i0 * LF);
        float a1 = pos * exp2f(-(i0 + 1.0f) * LF);
        float c0 = cosf(a0), s0 = sinf(a0), c1 = cosf(a1), s1 = sinf(a1);
        float qx = bf2f(q.x), qy = bf2f(q.y), qz = bf2f(q.z), qw = bf2f(q.w);
        q.x = f2bf(qx * c0 - qy * s0); q.y = f2bf(qx * s0 + qy * c0);
        q.z = f2bf(qz * c1 - qw * s1); q.w = f2bf(qz * s1 + qw * c1);
        float kx = bf2f(k.x), ky = bf2f(k.y), kz = bf2f(k.z), kw = bf2f(k.w);
        k.x = f2bf(kx * c0 - ky * s0); k.y = f2bf(kx * s0 + ky * c0);
        k.z = f2bf(kz * c1 - kw * s1); k.w = f2bf(kz * s1 + kw * c1);
    }
    size_t dst = ((size_t)((b * 16 + h) * 2048 + s)) * 256 + d;
    *(ushort4*)&qp[dst] = q;
    *(ushort4*)&kp[dst] = k;
}

// ---------- V transpose -> [b,h,d,s] ----------
__global__ __launch_bounds__(256) void v_transpose(const unsigned short* __restrict__ qkv,
                                                   unsigned short* __restrict__ vt) {
    int bid = blockIdx.x;
    int dt = bid & 3, st = (bid >> 2) & 31, bh = bid >> 7;
    int b = bh >> 4, h = bh & 15;
    __shared__ unsigned short t[64][72];
    int tid = threadIdx.x;
#pragma unroll
    for (int rep = 0; rep < 16; ++rep) {
        int idx = rep * 256 + tid;
        int r = idx >> 6, c = idx & 63;   // r: s-offset, c: d-offset
        t[r][c] = qkv[(size_t)(b * 2048 + st * 64 + r) * 12288 + 8192 + h * 256 + dt * 64 + c];
    }
    __syncthreads();
#pragma unroll
    for (int rep = 0; rep < 16; ++rep) {
        int idx = rep * 256 + tid;
        int r = idx >> 6, c = idx & 63;   // r: d-offset, c: s-offset
        vt[(size_t)(bh * 256 + dt * 64 + r) * 2048 + st * 64 + c] = t[c][r];
    }
}

// ---------- flash attention (causal), 4 waves x 16 q-rows, KV tile 32 ----------
// defer-max (T13, THR=8): skip m-update + O-rescale while per-tile max growth
// <= 8; P bounded by e^8, l_run tracks the same unnormalized scale.
__global__ __launch_bounds__(256) void attn_fwd(const unsigned short* __restrict__ Qp,
                                                const unsigned short* __restrict__ Kp,
                                                const unsigned short* __restrict__ Vt,
                                                unsigned short* __restrict__ Oa) {
    __shared__ __align__(16) unsigned short Ks[32 * 256];
    __shared__ __align__(16) unsigned short Vs[256 * 32];
    __shared__ __align__(16) unsigned short Ps[4][16 * 32];
    const int tid = threadIdx.x, lane = tid & 63, wv = tid >> 6;
    const int bh = blockIdx.x, qt = blockIdx.y;
    const int fr = lane & 15, fo = (lane >> 4) * 8;
    const unsigned short* Qb = Qp + (size_t)bh * 2048 * 256;
    const unsigned short* Kb = Kp + (size_t)bh * 2048 * 256;
    const unsigned short* Vb = Vt + (size_t)bh * 256 * 2048;
    const int qbase = qt * 64 + wv * 16;

    short8 qf[8];
#pragma unroll
    for (int c = 0; c < 8; ++c)
        qf[c] = *(const short8*)&Qb[(size_t)(qbase + fr) * 256 + c * 32 + fo];

    f32x4 o_acc[16] = {};
    float m_run[4] = {-1e30f, -1e30f, -1e30f, -1e30f};
    float l_run[4] = {0.f, 0.f, 0.f, 0.f};

    const int nkv = qt * 64 + 64;
    for (int kv0 = 0; kv0 < nkv; kv0 += 32) {
#pragma unroll
        for (int i = 0; i < 4; ++i) {
            int eb = (wv * 4 + i) * 512;
            load_lds16(&Kb[(size_t)(kv0 + (eb >> 8) + (lane >> 5)) * 256 + (lane & 31) * 8], &Ks[eb]);
        }
#pragma unroll
        for (int i = 0; i < 4; ++i) {
            int eb = (wv * 4 + i) * 512;
            load_lds16(&Vb[(size_t)((eb >> 5) + (lane >> 2)) * 2048 + kv0 + (lane & 3) * 8], &Vs[eb]);
        }
        __syncthreads();

        f32x4 sc[2] = {};
#pragma unroll
        for (int t = 0; t < 2; ++t)
#pragma unroll
            for (int c = 0; c < 8; ++c) {
                short8 kf = *(const short8*)&Ks[(t * 16 + fr) * 256 + c * 32 + fo];
                sc[t] = __builtin_amdgcn_mfma_f32_16x16x32_bf16(qf[c], kf, sc[t], 0, 0, 0);
            }

        float sv[2][4], pm[4];
#pragma unroll
        for (int j = 0; j < 4; ++j) {
            int qi = qbase + ((lane >> 4) << 2) + j;
#pragma unroll
            for (int t = 0; t < 2; ++t) {
                float x = sc[t][j] * 0.0625f;
                int kvi = kv0 + t * 16 + fr;
                sv[t][j] = (kvi > qi) ? -1e30f : x;
            }
            float p = fmaxf(sv[0][j], sv[1][j]);
#pragma unroll
            for (int off = 1; off < 16; off <<= 1)
                p = fmaxf(p, __shfl_xor(p, off));
            pm[j] = p;
        }
        bool need = (pm[0] > m_run[0] + 8.f) | (pm[1] > m_run[1] + 8.f) |
                    (pm[2] > m_run[2] + 8.f) | (pm[3] > m_run[3] + 8.f);
        if (__any(need)) {
#pragma unroll
            for (int j = 0; j < 4; ++j) {
                float mn = fmaxf(m_run[j], pm[j]);
                float al = __expf(m_run[j] - mn);
                m_run[j] = mn;
                l_run[j] *= al;
#pragma unroll
                for (int n = 0; n < 16; ++n) o_acc[n][j] *= al;
            }
        }
#pragma unroll
        for (int j = 0; j < 4; ++j) {
            float rs = 0.f;
#pragma unroll
            for (int t = 0; t < 2; ++t) {
                float p = __expf(sv[t][j] - m_run[j]);
                rs += p;
                Ps[wv][(((lane >> 4) << 2) + j) * 32 + t * 16 + fr] = f2bf(p);
            }
#pragma unroll
            for (int off = 1; off < 16; off <<= 1)
                rs += __shfl_xor(rs, off);
            l_run[j] += rs;
        }

        short8 pf = *(const short8*)&Ps[wv][fr * 32 + fo];
#pragma unroll
        for (int n = 0; n < 16; ++n) {
            short8 vf = *(const short8*)&Vs[(n * 16 + fr) * 32 + fo];
            o_acc[n] = __builtin_amdgcn_mfma_f32_16x16x32_bf16(pf, vf, o_acc[n], 0, 0, 0);
        }
        __syncthreads();
    }

    const int b = bh >> 4, h = bh & 15;
#pragma unroll
    for (int j = 0; j < 4; ++j) {
        float inv = 1.0f / l_run[j];
        int qrow = qbase + ((lane >> 4) << 2) + j;
        size_t base = ((size_t)(b * 2048 + qrow)) * 4096 + h * 256;
#pragma unroll
        for (int n = 0; n < 16; ++n)
            Oa[base + n * 16 + fr] = f2bf(o_acc[n][j] * inv);
    }
}

// ---------- launch ----------
extern "C" void kernel_launch(void* const* d_in, const int* in_sizes, int n_in,
                              void* d_out, int out_size, void* d_ws, size_t ws_size,
                              hipStream_t stream) {
    const float* hidden = (const float*)d_in[0];
    const int* positions = (const int*)d_in[1];
    const float* w_qkv = (const float*)d_in[2];
    const float* w_out = (const float*)d_in[3];
    float* out = (float*)d_out;

    const size_t MB32 = 33554432;   // 32 MiB
    char* ws = (char*)d_ws;
    unsigned short* hidden_bf = (unsigned short*)ws;              // 32 MB; later attn out
    unsigned short* wqkv_bf   = (unsigned short*)(ws + MB32);     // 96 MB; later q/k/vt
    unsigned short* qkv_bf    = (unsigned short*)(ws + 4 * MB32); // 96 MB; later wout_bf
    unsigned short* qp  = wqkv_bf;                                // 32 MB
    unsigned short* kp  = wqkv_bf + 16777216;                     // 32 MB
    unsigned short* vtp = wqkv_bf + 33554432;                     // 32 MB
    unsigned short* attn_bf = hidden_bf;                          // 32 MB (reuse)
    unsigned short* wout_bf = qkv_bf;                             // 32 MB (reuse)

    // 1. convert hidden (16.7M) and w_qkv (50.3M) to bf16
    conv_bf16<<<16384, 256, 0, stream>>>(hidden, hidden_bf, 4194304);
    conv_bf16<<<49152, 256, 0, stream>>>(w_qkv, wqkv_bf, 12582912);

    // 2. qkv = hidden @ w_qkv^T   (M=4096, N=12288, K=4096), bf16 out
    gemm256<true><<<16 * 48, 512, 0, stream>>>(hidden_bf, wqkv_bf, qkv_bf, 4096, 12288, 4096, 48);

    // 3. RoPE + repack q,k ; transpose v
    rope_repack<<<16384, 256, 0, stream>>>(qkv_bf, positions, qp, kp);
    v_transpose<<<4096, 256, 0, stream>>>(qkv_bf, vtp);

    // 4. causal flash attention -> attn_bf [4096, 4096]
    attn_fwd<<<dim3(32, 32), 256, 0, stream>>>(qp, kp, vtp, attn_bf);

    // 5. convert w_out, final projection (fp32 out)
    conv_bf16<<<16384, 256, 0, stream>>>(w_out, wout_bf, 4194304);
    gemm256<false><<<16 * 16, 512, 0, stream>>>(attn_bf, wout_bf, out, 4096, 4096, 4096, 16);
}

// Round 8
// 861.596 us; speedup vs baseline: 1.3229x; 1.0264x over previous
//
#include <hip/hip_runtime.h>

typedef __attribute__((ext_vector_type(8))) short short8;
typedef __attribute__((ext_vector_type(4))) float f32x4;

// ---------- helpers ----------
__device__ __forceinline__ unsigned short f2bf(float f) {
    union { float f; unsigned int u; } v; v.f = f;
    unsigned int u = v.u;
    unsigned int r = (u + 0x7FFFu + ((u >> 16) & 1u)) >> 16;
    return (unsigned short)r;
}
__device__ __forceinline__ float bf2f(unsigned short u) {
    union { unsigned int u; float f; } v; v.u = ((unsigned int)u) << 16;
    return v.f;
}
__device__ __forceinline__ void load_lds16(const void* g, void* l) {
    __builtin_amdgcn_global_load_lds(
        (const __attribute__((address_space(1))) void*)g,
        (__attribute__((address_space(3))) void*)l, 16, 0, 0);
}
#define BAR() asm volatile("s_barrier" ::: "memory")
#define WAITV(n) asm volatile("s_waitcnt vmcnt(" #n ")" ::: "memory")

// LDS swizzle (R3/R4, measured 0 conflicts): XOR row&7 (bits 7-9 at 128B row
// stride) into the 16B-slot index (bits 4-6). Involution on 16B chunks.
__device__ __forceinline__ int swz(int o) { return o ^ ((o >> 3) & 0x70); }

// ---------- fp32 -> bf16 convert ----------
__global__ __launch_bounds__(256) void conv_bf16(const float* __restrict__ in,
                                                 unsigned short* __restrict__ out, int n4) {
    int i = blockIdx.x * 256 + threadIdx.x;
    if (i >= n4) return;
    float4 v = ((const float4*)in)[i];
    ushort4 o;
    o.x = f2bf(v.x); o.y = f2bf(v.y); o.z = f2bf(v.z); o.w = f2bf(v.w);
    ((ushort4*)out)[i] = o;
}

// ---------- 256x256 8-phase GEMM (R4, best measured 362us, 0 conflicts) ----------
template <bool OUT_BF16>
__global__ __launch_bounds__(512, 2) void gemm256(const unsigned short* __restrict__ A,
                                                  const unsigned short* __restrict__ B,
                                                  void* __restrict__ Cv,
                                                  int M, int N, int K, int NBN) {
    __shared__ __align__(16) char smem[131072];
    const int tid = threadIdx.x;
    const int lane = tid & 63, wv = tid >> 6;
    const int wm = wv >> 2, wn = wv & 3;
    const int fr = lane & 15, fo = (lane >> 4) * 8;

    // bijective XCD swizzle (m204)
    const int nwg = gridDim.x, bid = blockIdx.x;
    const int q = nwg >> 3, r = nwg & 7, xcd = bid & 7, lid = bid >> 3;
    const int wg = (xcd < r ? xcd * (q + 1) : r * (q + 1) + (xcd - r) * q) + lid;
    const int bm = wg / NBN, bn = wg % NBN;

    const unsigned short* gA = A + (size_t)bm * 256 * K;
    const unsigned short* gB = B + (size_t)bn * 256 * K;

    // staging geometry: linear LDS dest o -> global element at swz(o)
    int srow[2][2], scol[2][2];
#pragma unroll
    for (int h = 0; h < 2; ++h)
#pragma unroll
        for (int rr = 0; rr < 2; ++rr) {
            int o = h * 16384 + rr * 8192 + tid * 16;
            int osw = swz(o);
            srow[h][rr] = osw >> 7;
            scol[h][rr] = (osw & 127) >> 1;
        }

    f32x4 acc[8][4] = {};
    short8 a[4][2], b[4][2];

    auto STAGE = [&](const unsigned short* g, int regionBase, int h, int t) {
#pragma unroll
        for (int rr = 0; rr < 2; ++rr)
            load_lds16(g + (size_t)srow[h][rr] * K + t * 64 + scol[h][rr],
                       smem + regionBase + h * 16384 + rr * 8192 + tid * 16);
    };
    auto RDA = [&](int bufBase, int mh) {
#pragma unroll
        for (int mf = 0; mf < 4; ++mf)
#pragma unroll
            for (int ks = 0; ks < 2; ++ks) {
                int o = swz((wm * 128 + mh * 64 + mf * 16 + fr) * 128 + (ks * 32 + fo) * 2);
                a[mf][ks] = *(const short8*)(smem + bufBase + o);
            }
    };
    auto RDB = [&](int bufBase, int nh) {
#pragma unroll
        for (int jj = 0; jj < 2; ++jj)
#pragma unroll
            for (int ks = 0; ks < 2; ++ks) {
                int o = swz((wn * 64 + (nh * 2 + jj) * 16 + fr) * 128 + (ks * 32 + fo) * 2);
                b[nh * 2 + jj][ks] = *(const short8*)(smem + bufBase + 32768 + o);
            }
    };
    auto MM = [&](int mh, int nh) {
        __builtin_amdgcn_s_setprio(1);
#pragma unroll
        for (int mf = 0; mf < 4; ++mf)
#pragma unroll
            for (int jj = 0; jj < 2; ++jj)
#pragma unroll
                for (int ks = 0; ks < 2; ++ks)
                    acc[mh * 4 + mf][nh * 2 + jj] = __builtin_amdgcn_mfma_f32_16x16x32_bf16(
                        a[mf][ks], b[nh * 2 + jj][ks], acc[mh * 4 + mf][nh * 2 + jj], 0, 0, 0);
        __builtin_amdgcn_s_setprio(0);
    };

    const int A0 = 0, B0 = 32768, A1 = 65536, B1 = 98304;

    // prologue: t0 (A,B) -> buf0; t1 (B,A) -> buf1. 16 loads.
    STAGE(gA, A0, 0, 0); STAGE(gA, A0, 1, 0);
    STAGE(gB, B0, 0, 0); STAGE(gB, B0, 1, 0);
    STAGE(gB, B1, 0, 1); STAGE(gB, B1, 1, 1);
    STAGE(gA, A1, 0, 1); STAGE(gA, A1, 1, 1);
    WAITV(8);
    BAR();
    RDA(A0, 0);
    RDB(A0, 0);

    const int NIT = K >> 7;  // K/128
    for (int i = 0; i < NIT; ++i) {
        const bool last = (i == NIT - 1);
        const int t2 = 2 * i + 2, t3 = 2 * i + 3;
        // P1
        RDB(A0, 1);
        MM(0, 0);
        if (i > 0) STAGE(gA, A1, 1, 2 * i + 1);
        BAR();
        // P2
        MM(0, 1);
        RDA(A0, 1);
        BAR();
        // P3
        MM(1, 1);
        if (!last) {
            STAGE(gB, B0, 0, t2);
            WAITV(2);
        } else {
            WAITV(0);
        }
        BAR();
        // P4
        MM(1, 0);
        RDA(A1, 0); RDB(A1, 0);
        if (!last) { STAGE(gB, B0, 1, t2); STAGE(gA, A0, 0, t2); }
        BAR();
        // P5
        RDB(A1, 1);
        MM(0, 0);
        if (!last) STAGE(gA, A0, 1, t2);
        BAR();
        // P6
        MM(0, 1);
        RDA(A1, 1);
        BAR();
        // P7
        MM(1, 1);
        if (!last) {
            STAGE(gB, B1, 0, t3);
            WAITV(2);
        }
        BAR();
        // P8
        MM(1, 0);
        if (!last) {
            RDA(A0, 0); RDB(A0, 0);
            STAGE(gB, B1, 1, t3); STAGE(gA, A1, 0, t3);
        }
        BAR();
    }

    // epilogue
    const size_t row0 = (size_t)bm * 256 + wm * 128 + ((lane >> 4) << 2);
    const int col0 = bn * 256 + wn * 64 + fr;
#pragma unroll
    for (int mf = 0; mf < 8; ++mf)
#pragma unroll
        for (int nf = 0; nf < 4; ++nf)
#pragma unroll
            for (int j = 0; j < 4; ++j) {
                size_t idx = (row0 + mf * 16 + j) * (size_t)N + col0 + nf * 16;
                if (OUT_BF16) ((unsigned short*)Cv)[idx] = f2bf(acc[mf][nf][j]);
                else          ((float*)Cv)[idx] = acc[mf][nf][j];
            }
}

// ---------- RoPE (interleaved, first 64 dims) + repack q,k -> [b,h,s,d] ----------
__global__ __launch_bounds__(256) void rope_repack(const unsigned short* __restrict__ qkv,
                                                   const int* __restrict__ positions,
                                                   unsigned short* __restrict__ qp,
                                                   unsigned short* __restrict__ kp) {
    int r = blockIdx.x * 4 + (threadIdx.x >> 6);   // (b,s,h) row, 0..65535
    int h = r & 15, s = (r >> 4) & 2047, b = r >> 15;
    int d = (threadIdx.x & 63) * 4;
    const unsigned short* src = qkv + (size_t)(b * 2048 + s) * 12288 + h * 256 + d;
    ushort4 q = *(const ushort4*)src;
    ushort4 k = *(const ushort4*)(src + 4096);
    if (d < 64) {
        float pos = (float)positions[s];
        const float LF = 0.4152410118609203f;      // log2(10000)/32
        float i0 = (float)(d >> 1);
        float a0 = pos * exp2f(-i0 * LF);
        float a1 = pos * exp2f(-(i0 + 1.0f) * LF);
        float c0 = cosf(a0), s0 = sinf(a0), c1 = cosf(a1), s1 = sinf(a1);
        float qx = bf2f(q.x), qy = bf2f(q.y), qz = bf2f(q.z), qw = bf2f(q.w);
        q.x = f2bf(qx * c0 - qy * s0); q.y = f2bf(qx * s0 + qy * c0);
        q.z = f2bf(qz * c1 - qw * s1); q.w = f2bf(qz * s1 + qw * c1);
        float kx = bf2f(k.x), ky = bf2f(k.y), kz = bf2f(k.z), kw = bf2f(k.w);
        k.x = f2bf(kx * c0 - ky * s0); k.y = f2bf(kx * s0 + ky * c0);
        k.z = f2bf(kz * c1 - kw * s1); k.w = f2bf(kz * s1 + kw * c1);
    }
    size_t dst = ((size_t)((b * 16 + h) * 2048 + s)) * 256 + d;
    *(ushort4*)&qp[dst] = q;
    *(ushort4*)&kp[dst] = k;
}

// ---------- V transpose -> [b,h,d,s] ----------
__global__ __launch_bounds__(256) void v_transpose(const unsigned short* __restrict__ qkv,
                                                   unsigned short* __restrict__ vt) {
    int bid = blockIdx.x;
    int dt = bid & 3, st = (bid >> 2) & 31, bh = bid >> 7;
    int b = bh >> 4, h = bh & 15;
    __shared__ unsigned short t[64][72];
    int tid = threadIdx.x;
#pragma unroll
    for (int rep = 0; rep < 16; ++rep) {
        int idx = rep * 256 + tid;
        int r = idx >> 6, c = idx & 63;   // r: s-offset, c: d-offset
        t[r][c] = qkv[(size_t)(b * 2048 + st * 64 + r) * 12288 + 8192 + h * 256 + dt * 64 + c];
    }
    __syncthreads();
#pragma unroll
    for (int rep = 0; rep < 16; ++rep) {
        int idx = rep * 256 + tid;
        int r = idx >> 6, c = idx & 63;   // r: d-offset, c: s-offset
        vt[(size_t)(bh * 256 + dt * 64 + r) * 2048 + st * 64 + c] = t[c][r];
    }
}

// ---------- flash attention (causal), 4 waves x 16 q-rows, KV tile 32 ----------
// LDS swizzles (new this round):
//  Ks [32 rows][512B]: 8-lane groups previously hit ONE 16B slot (8-way).
//    Fix: o ^= ((o>>5)&0x70)  (XOR row&7 into slot bits 4-6; R3-verified class).
//  Vs [256 rows][64B]: only 2 slot bits; o ^= (((o>>6)^(o>>8))&3)<<4
//    (slot ^= (row^(row>>2))&3) -> 8 consecutive rows hit all 8 bank groups
//    (enumerated: classes {0,5,2,7,1,4,3,6}).
// Both staged via linear gload_lds dest + pre-swizzled global source
// (involutions), read at swizzled offsets. defer-max (T13, THR=8) kept.
__global__ __launch_bounds__(256) void attn_fwd(const unsigned short* __restrict__ Qp,
                                                const unsigned short* __restrict__ Kp,
                                                const unsigned short* __restrict__ Vt,
                                                unsigned short* __restrict__ Oa) {
    __shared__ __align__(16) unsigned short Ks[32 * 256];
    __shared__ __align__(16) unsigned short Vs[256 * 32];
    __shared__ __align__(16) unsigned short Ps[4][16 * 32];
    const int tid = threadIdx.x, lane = tid & 63, wv = tid >> 6;
    const int bh = blockIdx.x, qt = blockIdx.y;
    const int fr = lane & 15, fo = (lane >> 4) * 8;
    const unsigned short* Qb = Qp + (size_t)bh * 2048 * 256;
    const unsigned short* Kb = Kp + (size_t)bh * 2048 * 256;
    const unsigned short* Vb = Vt + (size_t)bh * 256 * 2048;
    const int qbase = qt * 64 + wv * 16;

    short8 qf[8];
#pragma unroll
    for (int c = 0; c < 8; ++c)
        qf[c] = *(const short8*)&Qb[(size_t)(qbase + fr) * 256 + c * 32 + fo];

    f32x4 o_acc[16] = {};
    float m_run[4] = {-1e30f, -1e30f, -1e30f, -1e30f};
    float l_run[4] = {0.f, 0.f, 0.f, 0.f};

    const int nkv = qt * 64 + 64;
    for (int kv0 = 0; kv0 < nkv; kv0 += 32) {
        // stage K tile [32][256] swizzled
#pragma unroll
        for (int i = 0; i < 4; ++i) {
            int ob = (wv * 4 + i) * 1024 + lane * 16;          // dest byte off
            int osw = ob ^ ((ob >> 5) & 0x70);
            int row = kv0 + (ob >> 9);
            load_lds16(&Kb[(size_t)row * 256 + ((osw & 511) >> 1)],
                       (char*)Ks + (wv * 4 + i) * 1024);
        }
        // stage V^T tile [256][32] swizzled
#pragma unroll
        for (int i = 0; i < 4; ++i) {
            int ob = (wv * 4 + i) * 1024 + lane * 16;
            int osw = ob ^ ((((ob >> 6) ^ (ob >> 8)) & 3) << 4);
            int drow = ob >> 6;
            load_lds16(&Vb[(size_t)drow * 2048 + kv0 + ((osw & 63) >> 1)],
                       (char*)Vs + (wv * 4 + i) * 1024);
        }
        __syncthreads();

        f32x4 sc[2] = {};
#pragma unroll
        for (int t = 0; t < 2; ++t)
#pragma unroll
            for (int c = 0; c < 8; ++c) {
                int o = (t * 16 + fr) * 512 + (c * 32 + fo) * 2;
                o ^= (o >> 5) & 0x70;
                short8 kf = *(const short8*)((const char*)Ks + o);
                sc[t] = __builtin_amdgcn_mfma_f32_16x16x32_bf16(qf[c], kf, sc[t], 0, 0, 0);
            }

        float sv[2][4], pm[4];
#pragma unroll
        for (int j = 0; j < 4; ++j) {
            int qi = qbase + ((lane >> 4) << 2) + j;
#pragma unroll
            for (int t = 0; t < 2; ++t) {
                float x = sc[t][j] * 0.0625f;
                int kvi = kv0 + t * 16 + fr;
                sv[t][j] = (kvi > qi) ? -1e30f : x;
            }
            float p = fmaxf(sv[0][j], sv[1][j]);
#pragma unroll
            for (int off = 1; off < 16; off <<= 1)
                p = fmaxf(p, __shfl_xor(p, off));
            pm[j] = p;
        }
        bool need = (pm[0] > m_run[0] + 8.f) | (pm[1] > m_run[1] + 8.f) |
                    (pm[2] > m_run[2] + 8.f) | (pm[3] > m_run[3] + 8.f);
        if (__any(need)) {
#pragma unroll
            for (int j = 0; j < 4; ++j) {
                float mn = fmaxf(m_run[j], pm[j]);
                float al = __expf(m_run[j] - mn);
                m_run[j] = mn;
                l_run[j] *= al;
#pragma unroll
                for (int n = 0; n < 16; ++n) o_acc[n][j] *= al;
            }
        }
#pragma unroll
        for (int j = 0; j < 4; ++j) {
            float rs = 0.f;
#pragma unroll
            for (int t = 0; t < 2; ++t) {
                float p = __expf(sv[t][j] - m_run[j]);
                rs += p;
                Ps[wv][(((lane >> 4) << 2) + j) * 32 + t * 16 + fr] = f2bf(p);
            }
#pragma unroll
            for (int off = 1; off < 16; off <<= 1)
                rs += __shfl_xor(rs, off);
            l_run[j] += rs;
        }

        short8 pf = *(const short8*)&Ps[wv][fr * 32 + fo];
#pragma unroll
        for (int n = 0; n < 16; ++n) {
            int o = (n * 16 + fr) * 64 + fo * 2;
            o ^= (((o >> 6) ^ (o >> 8)) & 3) << 4;
            short8 vf = *(const short8*)((const char*)Vs + o);
            o_acc[n] = __builtin_amdgcn_mfma_f32_16x16x32_bf16(pf, vf, o_acc[n], 0, 0, 0);
        }
        __syncthreads();
    }

    const int b = bh >> 4, h = bh & 15;
#pragma unroll
    for (int j = 0; j < 4; ++j) {
        float inv = 1.0f / l_run[j];
        int qrow = qbase + ((lane >> 4) << 2) + j;
        size_t base = ((size_t)(b * 2048 + qrow)) * 4096 + h * 256;
#pragma unroll
        for (int n = 0; n < 16; ++n)
            Oa[base + n * 16 + fr] = f2bf(o_acc[n][j] * inv);
    }
}

// ---------- launch ----------
extern "C" void kernel_launch(void* const* d_in, const int* in_sizes, int n_in,
                              void* d_out, int out_size, void* d_ws, size_t ws_size,
                              hipStream_t stream) {
    const float* hidden = (const float*)d_in[0];
    const int* positions = (const int*)d_in[1];
    const float* w_qkv = (const float*)d_in[2];
    const float* w_out = (const float*)d_in[3];
    float* out = (float*)d_out;

    const size_t MB32 = 33554432;   // 32 MiB
    char* ws = (char*)d_ws;
    unsigned short* hidden_bf = (unsigned short*)ws;              // 32 MB; later attn out
    unsigned short* wqkv_bf   = (unsigned short*)(ws + MB32);     // 96 MB; later q/k/vt
    unsigned short* qkv_bf    = (unsigned short*)(ws + 4 * MB32); // 96 MB; later wout_bf
    unsigned short* qp  = wqkv_bf;                                // 32 MB
    unsigned short* kp  = wqkv_bf + 16777216;                     // 32 MB
    unsigned short* vtp = wqkv_bf + 33554432;                     // 32 MB
    unsigned short* attn_bf = hidden_bf;                          // 32 MB (reuse)
    unsigned short* wout_bf = qkv_bf;                             // 32 MB (reuse)

    // 1. convert hidden (16.7M) and w_qkv (50.3M) to bf16
    conv_bf16<<<16384, 256, 0, stream>>>(hidden, hidden_bf, 4194304);
    conv_bf16<<<49152, 256, 0, stream>>>(w_qkv, wqkv_bf, 12582912);

    // 2. qkv = hidden @ w_qkv^T   (M=4096, N=12288, K=4096), bf16 out
    gemm256<true><<<16 * 48, 512, 0, stream>>>(hidden_bf, wqkv_bf, qkv_bf, 4096, 12288, 4096, 48);

    // 3. RoPE + repack q,k ; transpose v
    rope_repack<<<16384, 256, 0, stream>>>(qkv_bf, positions, qp, kp);
    v_transpose<<<4096, 256, 0, stream>>>(qkv_bf, vtp);

    // 4. causal flash attention -> attn_bf [4096, 4096]
    attn_fwd<<<dim3(32, 32), 256, 0, stream>>>(qp, kp, vtp, attn_bf);

    // 5. convert w_out, final projection (fp32 out)
    conv_bf16<<<16384, 256, 0, stream>>>(w_out, wout_bf, 4194304);
    gemm256<false><<<16 * 16, 512, 0, stream>>>(attn_bf, wout_bf, out, 4096, 4096, 4096, 16);
}